// Round 1
// baseline (51.568 us; speedup 1.0000x reference)
//
#include <hip/hip_runtime.h>
#include <hip/hip_bf16.h>

// ZDecoder: qs[b,c,o] = MLP(concat(V(c), phi(b)))
// Layer-1 separability: h1[b,c] = relu(A[c] + P[b]),
//   A[c] = sum_l Bt[l][(c>>3l)&7], Bt[l][r][h] = sum_z w1[h][16l+z]*rp[l][r][z]
//   P[b][h] = b1[h] + sum_p w1[h][64+p]*phi[b][p]
// Layers 2/3 via bf16 MFMA 16x16x32, fp32 accum; output write-bound (128 MiB).

typedef __attribute__((ext_vector_type(8))) short short8;
typedef __attribute__((ext_vector_type(4))) float f32x4;

#define MFMA16(a, b, c) __builtin_amdgcn_mfma_f32_16x16x32_bf16(a, b, c, 0, 0, 0)

__device__ __forceinline__ short f2bf(float x) {
    union { __hip_bfloat16 b; short s; } u;
    u.b = __float2bfloat16(x);
    return u.s;
}

__device__ __forceinline__ float4 ldg4(const float* p) {
    return *reinterpret_cast<const float4*>(p);
}

__global__ __launch_bounds__(256, 3)
void zdec_kernel(const float* __restrict__ phi, const float* __restrict__ rp,
                 const float* __restrict__ w1, const float* __restrict__ b1,
                 const float* __restrict__ w2, const float* __restrict__ b2,
                 const float* __restrict__ w3, const float* __restrict__ b3,
                 float* __restrict__ out)
{
    __shared__ float Bt[2048];      // [4 levels][8 regions][64 h]
    __shared__ float At[4096];      // [64 combos][64 h], XOR-swizzled
    __shared__ float Pt[1024];      // [16 batches][64 h], linear
    __shared__ float H2s[4][1024];  // per-wave transpose scratch, XOR-swizzled

    const int t  = threadIdx.x;
    const int cb = blockIdx.x & 63;   // combo tile: 64 tiles of 64 combos
    const int bb = blockIdx.x >> 6;   // batch tile: 16 tiles of 16 batches
    const int c0 = cb << 6;
    const int b0 = bb << 4;

    // ---------------- setup: B table ----------------
    {
        const int l = t >> 6, h = t & 63;
        float ws[16];
#pragma unroll
        for (int z4 = 0; z4 < 4; ++z4) {
            const float4 v = ldg4(w1 + h * 128 + l * 16 + z4 * 4);
            ws[z4*4+0] = v.x; ws[z4*4+1] = v.y; ws[z4*4+2] = v.z; ws[z4*4+3] = v.w;
        }
#pragma unroll
        for (int r = 0; r < 8; ++r) {
            float acc = 0.f;
#pragma unroll
            for (int z4 = 0; z4 < 4; ++z4) {
                const float4 v = ldg4(rp + (l * 8 + r) * 16 + z4 * 4);
                acc += ws[z4*4+0]*v.x + ws[z4*4+1]*v.y + ws[z4*4+2]*v.z + ws[z4*4+3]*v.w;
            }
            Bt[(l * 8 + r) * 64 + h] = acc;
        }
    }
    // ---------------- setup: P rows ----------------
    {
        const int h = t & 63, bg = t >> 6;
        const float bias = b1[h];
        float acc[4] = {bias, bias, bias, bias};
#pragma unroll
        for (int p4 = 0; p4 < 16; ++p4) {
            const float4 wvv = ldg4(w1 + h * 128 + 64 + p4 * 4);
#pragma unroll
            for (int bj = 0; bj < 4; ++bj) {
                const float4 pv = ldg4(phi + (b0 + bg * 4 + bj) * 64 + p4 * 4);
                acc[bj] += wvv.x * pv.x + wvv.y * pv.y + wvv.z * pv.z + wvv.w * pv.w;
            }
        }
#pragma unroll
        for (int bj = 0; bj < 4; ++bj)
            Pt[(bg * 4 + bj) * 64 + h] = acc[bj];
    }
    __syncthreads();
    // ---------------- setup: A tile (swizzled) ----------------
    {
        const int h = t & 63, cg = t >> 6;
        const int r2 = (c0 >> 6) & 7, r3 = (c0 >> 9) & 7;  // uniform over 64-combo tile
        const float c23 = Bt[(16 + r2) * 64 + h] + Bt[(24 + r3) * 64 + h];
#pragma unroll
        for (int cc = 0; cc < 16; ++cc) {
            const int ct = cg * 16 + cc;
            const float v = c23 + Bt[(ct & 7) * 64 + h] + Bt[(8 + ((ct >> 3) & 7)) * 64 + h];
            At[ct * 64 + (h ^ ((ct & 15) << 2))] = v;
        }
    }
    __syncthreads();

    // ---------------- main: per-wave 16 combos x 16 batches ----------------
    const int lane = t & 63;
    const int wid  = t >> 6;
    const int q = lane >> 4;      // quarter-wave group
    const int s = lane & 15;
    const int mct = (wid << 4) + s;  // this lane's combo row for the A-operand

    // weight fragments: B-operand = [N-row][K contiguous 8] from row-major NxK
    short8 w2f[4][2];
#pragma unroll
    for (int nt = 0; nt < 4; ++nt)
#pragma unroll
        for (int kt = 0; kt < 2; ++kt) {
            const float* src = w2 + (nt * 16 + s) * 64 + kt * 32 + q * 8;
            const float4 v0 = ldg4(src), v1 = ldg4(src + 4);
            short8 f;
            f[0]=f2bf(v0.x); f[1]=f2bf(v0.y); f[2]=f2bf(v0.z); f[3]=f2bf(v0.w);
            f[4]=f2bf(v1.x); f[5]=f2bf(v1.y); f[6]=f2bf(v1.z); f[7]=f2bf(v1.w);
            w2f[nt][kt] = f;
        }
    short8 w3f[2][2];
#pragma unroll
    for (int nt = 0; nt < 2; ++nt)
#pragma unroll
        for (int kt = 0; kt < 2; ++kt) {
            const float* src = w3 + (nt * 16 + s) * 64 + kt * 32 + q * 8;
            const float4 v0 = ldg4(src), v1 = ldg4(src + 4);
            short8 f;
            f[0]=f2bf(v0.x); f[1]=f2bf(v0.y); f[2]=f2bf(v0.z); f[3]=f2bf(v0.w);
            f[4]=f2bf(v1.x); f[5]=f2bf(v1.y); f[6]=f2bf(v1.z); f[7]=f2bf(v1.w);
            w3f[nt][kt] = f;
        }
    float b2v[4];
#pragma unroll
    for (int nt = 0; nt < 4; ++nt) b2v[nt] = b2[nt * 16 + s];
    float b3v[2];
    b3v[0] = b3[s]; b3v[1] = b3[16 + s];

    // A fragment for this lane's combo (kept in regs across the batch loop)
    float af[16];
    {
        const int amask = (mct & 15) << 2;
#pragma unroll
        for (int ch = 0; ch < 4; ++ch) {
            const int hc = (ch >> 1) * 32 + q * 8 + (ch & 1) * 4;
            const float4 v = *reinterpret_cast<const float4*>(At + mct * 64 + (hc ^ amask));
            af[ch*4+0]=v.x; af[ch*4+1]=v.y; af[ch*4+2]=v.z; af[ch*4+3]=v.w;
        }
    }

    float* hs = H2s[wid];
    const int hsmask = s << 2;
    float* outp = out + (b0 * 4096 + c0 + (wid << 4)) * 32 + q * 128 + s;

    for (int bi = 0; bi < 16; ++bi) {
        // P fragment (broadcast reads)
        float pf[16];
#pragma unroll
        for (int ch = 0; ch < 4; ++ch) {
            const int hc = (ch >> 1) * 32 + q * 8 + (ch & 1) * 4;
            const float4 v = *reinterpret_cast<const float4*>(Pt + bi * 64 + hc);
            pf[ch*4+0]=v.x; pf[ch*4+1]=v.y; pf[ch*4+2]=v.z; pf[ch*4+3]=v.w;
        }
        // h1 = relu(A + P), fp32 -> bf16
        short8 h1f0, h1f1;
#pragma unroll
        for (int j = 0; j < 8; ++j) h1f0[j] = f2bf(fmaxf(af[j]     + pf[j],     0.f));
#pragma unroll
        for (int j = 0; j < 8; ++j) h1f1[j] = f2bf(fmaxf(af[8 + j] + pf[8 + j], 0.f));

        // layer 2: D2[m=16 combos][g=64], bias via acc-init
        f32x4 a2[4];
#pragma unroll
        for (int nt = 0; nt < 4; ++nt) {
            f32x4 acc = {b2v[nt], b2v[nt], b2v[nt], b2v[nt]};
            acc = MFMA16(h1f0, w2f[nt][0], acc);
            acc = MFMA16(h1f1, w2f[nt][1], acc);
            a2[nt] = acc;
        }
        // relu + transpose D-layout -> A-layout via per-wave swizzled LDS
#pragma unroll
        for (int nt = 0; nt < 4; ++nt)
#pragma unroll
            for (int r = 0; r < 4; ++r) {
                const int m = q * 4 + r;
                const int g = nt * 16 + s;
                hs[m * 64 + (g ^ ((m & 15) << 2))] = fmaxf(a2[nt][r], 0.f);
            }
        asm volatile("s_waitcnt lgkmcnt(0)" ::: "memory");  // wave-sync LDS transpose
        short8 h2f0, h2f1;
        {
            float tmp[16];
#pragma unroll
            for (int ch = 0; ch < 4; ++ch) {
                const int hc = (ch >> 1) * 32 + q * 8 + (ch & 1) * 4;
                const float4 v = *reinterpret_cast<const float4*>(hs + s * 64 + (hc ^ hsmask));
                tmp[ch*4+0]=v.x; tmp[ch*4+1]=v.y; tmp[ch*4+2]=v.z; tmp[ch*4+3]=v.w;
            }
#pragma unroll
            for (int j = 0; j < 8; ++j) h2f0[j] = f2bf(tmp[j]);
#pragma unroll
            for (int j = 0; j < 8; ++j) h2f1[j] = f2bf(tmp[8 + j]);
        }
        // layer 3 + store
        float* op = outp + bi * 131072;  // (b0+bi)*4096*32
#pragma unroll
        for (int nt = 0; nt < 2; ++nt) {
            f32x4 acc = {b3v[nt], b3v[nt], b3v[nt], b3v[nt]};
            acc = MFMA16(h2f0, w3f[nt][0], acc);
            acc = MFMA16(h2f1, w3f[nt][1], acc);
#pragma unroll
            for (int r = 0; r < 4; ++r)
                op[r * 32 + nt * 16] = acc[r];
        }
        // WAR on hs across iterations is safe: same-wave LDS ops retire in order.
    }
}

extern "C" void kernel_launch(void* const* d_in, const int* in_sizes, int n_in,
                              void* d_out, int out_size, void* d_ws, size_t ws_size,
                              hipStream_t stream) {
    const float* phi = (const float*)d_in[0];
    const float* rp  = (const float*)d_in[1];
    const float* w1  = (const float*)d_in[2];
    const float* b1  = (const float*)d_in[3];
    const float* w2  = (const float*)d_in[4];
    const float* b2  = (const float*)d_in[5];
    const float* w3  = (const float*)d_in[6];
    const float* b3  = (const float*)d_in[7];
    (void)in_sizes; (void)n_in; (void)out_size; (void)d_ws; (void)ws_size;

    zdec_kernel<<<dim3(1024), dim3(256), 0, stream>>>(
        phi, rp, w1, b1, w2, b2, w3, b3, (float*)d_out);
}